// Round 20
// baseline (139.401 us; speedup 1.0000x reference)
//
#include <hip/hip_runtime.h>
#include <stdint.h>

// Round 20: terminal validation of the R19 consolidation (132.8us verified) with one
// index-only lever: qkv grid-order swap (mt=bx/12, y=bx%12) so 12 consecutive blocks
// share one A-panel concurrently (A-panel L3->L2 broadcast reuse). Bijective; no
// per-block code change. Everything else R19-exact.

typedef __attribute__((ext_vector_type(4))) float f32x4;
typedef __attribute__((ext_vector_type(8))) short short8;
typedef __attribute__((ext_vector_type(4))) short short4b;

__device__ __forceinline__ short f2bf(float f) {
    union { float f; uint32_t u; } v; v.f = f;
    uint32_t r = (v.u + 0x7FFFu + ((v.u >> 16) & 1u)) >> 16;   // RNE
    return (short)r;
}
__device__ __forceinline__ float bf2f(short s) {
    union { uint32_t u; float f; } v; v.u = ((uint32_t)(uint16_t)s) << 16; return v.f;
}
__device__ __forceinline__ float sigm(float x) { return 1.0f / (1.0f + __expf(-x)); }

__device__ __forceinline__ void gload_lds16(const void* g, void* l) {
    __builtin_amdgcn_global_load_lds(
        (const __attribute__((address_space(1))) void*)g,
        (__attribute__((address_space(3))) void*)l, 16, 0, 0);
}

#define VMBAR() asm volatile("s_waitcnt vmcnt(0)\n\ts_barrier" ::: "memory")

// ---------------------------------------------------------------- K0: convert X + prep weights
__global__ __launch_bounds__(256) void fused_prep(
    const float* __restrict__ X, const float* __restrict__ Wq,
    const float* __restrict__ Wv, const float* __restrict__ Wk,
    short* __restrict__ Xb, short* __restrict__ Wt)
{
    __shared__ float T[64 * 68];
    if (blockIdx.x < 4096) {
        size_t i = (size_t)blockIdx.x * 256 + threadIdx.x;     // 8 floats/thread
        const float4* src = reinterpret_cast<const float4*>(X) + i * 2;
        float4 a = src[0], b = src[1];
        short8 o;
        o[0] = f2bf(a.x); o[1] = f2bf(a.y); o[2] = f2bf(a.z); o[3] = f2bf(a.w);
        o[4] = f2bf(b.x); o[5] = f2bf(b.y); o[6] = f2bf(b.z); o[7] = f2bf(b.w);
        *reinterpret_cast<short8*>(Xb + i * 8) = o;
        return;
    }
    int bid = blockIdx.x - 4096;
    int w = bid >> 6;                 // 0..2
    int tile = bid & 63;
    int n0 = (tile & 7) * 64;
    int k0 = (tile >> 3) * 64;
    const float* W = (w == 0) ? Wq : (w == 1) ? Wv : Wk;
    int t = threadIdx.x;
    int tr = t >> 4, tc = t & 15;
    for (int rr = 0; rr < 4; ++rr) {
        int row = rr * 16 + tr;       // k-local
        float4 v = *reinterpret_cast<const float4*>(&W[(size_t)(k0 + row) * 512 + n0 + tc * 4]);
        T[row * 68 + tc * 4 + 0] = v.x;
        T[row * 68 + tc * 4 + 1] = v.y;
        T[row * 68 + tc * 4 + 2] = v.z;
        T[row * 68 + tc * 4 + 3] = v.w;
    }
    __syncthreads();
    for (int wr = 0; wr < 4; ++wr) {
        int nl = wr * 16 + tr;        // n-local
        short4b o;
        for (int i = 0; i < 4; ++i) o[i] = f2bf(T[(tc * 4 + i) * 68 + nl]);
        *reinterpret_cast<short4b*>(&Wt[((size_t)(w * 512 + n0 + nl)) * 512 + k0 + tc * 4]) = o;
    }
}

// ---------------------------------------------------------------- K2: QKV GEMM (R19 + grid swap)
__global__ __launch_bounds__(256, 2) void qkv_gemm(
    const short* __restrict__ Xb,    // [16384][512] bf16
    const short* __restrict__ Wt,    // [3][512 n][512 k] bf16
    short* __restrict__ Qb, short* __restrict__ Kb, short* __restrict__ VtG)
{
    __shared__ short SMEM[2][16384];   // per buf: As[128][64] | Bs[128][64]; buf0 reused as Ts

    int bx = blockIdx.x;
    int mt = bx / 12;                  // consecutive bids share one A-panel
    int y = bx % 12;
    int w = y >> 2, nt = y & 3;
    int m0 = mt * 128, n0 = nt * 128;

    int tid = threadIdx.x;
    int wv = tid >> 6, lane = tid & 63;
    int wr = wv >> 1, wc = wv & 1;
    int ln = lane & 15, hi = lane >> 4;

    f32x4 acc[4][4];
#pragma unroll
    for (int i = 0; i < 4; ++i)
#pragma unroll
        for (int j = 0; j < 4; ++j) acc[i][j] = {0.f, 0.f, 0.f, 0.f};

    const short* Asrc = Xb + (size_t)m0 * 512;
    const short* Bsrc = Wt + (size_t)w * 512 * 512 + (size_t)n0 * 512;

    int srow = wv * 8 + (lane >> 3);
    int ssc0 = (lane & 7) * 8;

#define QSTAGE(ko, buf)                                                            \
    {                                                                              \
        int _k0 = (ko) * 64;                                                       \
        _Pragma("unroll")                                                          \
        for (int _j = 0; _j < 4; ++_j) {                                           \
            int _r = srow + _j * 32;                                               \
            int _sc = ssc0 ^ ((_r & 7) << 3);                                      \
            gload_lds16(Asrc + (size_t)_r * 512 + _k0 + _sc,                       \
                        &SMEM[buf][(wv * 8 + _j * 32) * 64]);                      \
        }                                                                          \
        _Pragma("unroll")                                                          \
        for (int _j = 0; _j < 4; ++_j) {                                           \
            int _r = srow + _j * 32;                                               \
            int _sc = ssc0 ^ ((_r & 7) << 3);                                      \
            gload_lds16(Bsrc + (size_t)_r * 512 + _k0 + _sc,                       \
                        &SMEM[buf][8192 + (wv * 8 + _j * 32) * 64]);               \
        }                                                                          \
    }

    QSTAGE(0, 0);
    for (int ko = 0; ko < 8; ++ko) {
        VMBAR();                                     // buf[ko&1] staged, all waves aligned
        if (ko + 1 < 8) QSTAGE(ko + 1, (ko + 1) & 1);
        const short* As = SMEM[ko & 1];
        const short* Bs = SMEM[ko & 1] + 8192;
#pragma unroll
        for (int kk = 0; kk < 2; ++kk) {
            int kof = kk * 32 + hi * 8;
            int sw = (ln & 7) << 3;
            short8 af[4], bf[4];
#pragma unroll
            for (int mf = 0; mf < 4; ++mf)
                af[mf] = *reinterpret_cast<const short8*>(&As[(wr * 64 + mf * 16 + ln) * 64 + (kof ^ sw)]);
#pragma unroll
            for (int nf = 0; nf < 4; ++nf)
                bf[nf] = *reinterpret_cast<const short8*>(&Bs[(wc * 64 + nf * 16 + ln) * 64 + (kof ^ sw)]);
#pragma unroll
            for (int mf = 0; mf < 4; ++mf)
#pragma unroll
                for (int nf = 0; nf < 4; ++nf)
                    acc[mf][nf] = __builtin_amdgcn_mfma_f32_16x16x32_bf16(af[mf], bf[nf], acc[mf][nf], 0, 0, 0);
        }
    }
    __syncthreads();                                 // loop done -> SMEM reusable
#undef QSTAGE

    short* Ts = SMEM[0];                             // [128][128] shorts, col ^ ((row&7)<<3)
    if (w < 2) {
        // Q/K: sigmoid -> bf16 -> LDS (swizzled) -> coalesced 16B row stores
#pragma unroll
        for (int mf = 0; mf < 4; ++mf)
#pragma unroll
            for (int nf = 0; nf < 4; ++nf)
#pragma unroll
                for (int j = 0; j < 4; ++j) {
                    int rl = wr * 64 + mf * 16 + hi * 4 + j;
                    int cl = wc * 64 + nf * 16 + ln;
                    Ts[rl * 128 + (cl ^ ((rl & 7) << 3))] = f2bf(sigm(acc[mf][nf][j]));
                }
        __syncthreads();
        short* O = (w == 0) ? Qb : Kb;
        int r = tid >> 1, h = tid & 1;
#pragma unroll
        for (int i = 0; i < 8; ++i) {
            int c8 = h * 64 + i * 8;
            short8 v = *reinterpret_cast<const short8*>(&Ts[r * 128 + (c8 ^ ((r & 7) << 3))]);
            *reinterpret_cast<short8*>(&O[(size_t)(m0 + r) * 512 + n0 + c8]) = v;
        }
    } else {
        // V: transpose via LDS, store Vt[b][d][s]
#pragma unroll
        for (int mf = 0; mf < 4; ++mf)
#pragma unroll
            for (int nf = 0; nf < 4; ++nf)
#pragma unroll
                for (int j = 0; j < 4; ++j) {
                    int ml = wr * 64 + mf * 16 + hi * 4 + j;       // s-local
                    int nl = wc * 64 + nf * 16 + ln;               // d-local
                    Ts[nl * 128 + (ml ^ ((nl & 7) << 3))] = f2bf(sigm(acc[mf][nf][j]));
                }
        __syncthreads();
        int bb = m0 >> 11;
        int s0 = m0 & 2047;
        int d = tid >> 1, h = tid & 1;
#pragma unroll
        for (int i = 0; i < 8; ++i) {
            int s8 = h * 64 + i * 8;
            short8 v = *reinterpret_cast<const short8*>(&Ts[d * 128 + (s8 ^ ((d & 7) << 3))]);
            *reinterpret_cast<short8*>(&VtG[((size_t)(bb * 512 + n0 + d)) * 2048 + s0 + s8]) = v;
        }
    }
}

// ---------------------------------------------------------------- PA: score pass (R8-exact)
__global__ __launch_bounds__(256) void score_pass(
    const short* __restrict__ Qb, const short* __restrict__ Kb,
    short* __restrict__ Pc, float* __restrict__ Dpart)
{
    __shared__ short SMEM[128 * 128];       // As | Bs
    __shared__ float psum[2][128];
    short* As = SMEM;
    short* Bs = SMEM + 128 * 64;

    const float scale = 0.044194173824159216f;   // 1/sqrt(512)

    int bid = blockIdx.x;
    int b = bid & 7;
    int idx = bid >> 3;
    int ti = 0;
    while ((ti + 1) * (ti + 2) / 2 <= idx) ++ti;
    int tj = idx - ti * (ti + 1) / 2;
    int m0 = ti * 128, n0 = tj * 128;

    int tid = threadIdx.x;
    int w = tid >> 6, lane = tid & 63;
    int wr = w >> 1, wc = w & 1;
    int ln = lane & 15, hi = lane >> 4;

    const short* Qsrc = Qb + (size_t)b * 2048 * 512 + (size_t)m0 * 512;
    const short* Ksrc = Kb + (size_t)b * 2048 * 512 + (size_t)n0 * 512;

    f32x4 acc[4][4];
#pragma unroll
    for (int i = 0; i < 4; ++i)
#pragma unroll
        for (int j = 0; j < 4; ++j) acc[i][j] = {0.f, 0.f, 0.f, 0.f};

    for (int ko = 0; ko < 8; ++ko) {
        int k0 = ko * 64;
#pragma unroll
        for (int j = 0; j < 4; ++j) {
            int r = w * 8 + j * 32 + (lane >> 3);
            int sc = ((lane & 7) * 8) ^ ((r & 7) << 3);
            gload_lds16(Qsrc + (size_t)r * 512 + k0 + sc, &As[(w * 8 + j * 32) * 64]);
        }
#pragma unroll
        for (int j = 0; j < 4; ++j) {
            int r = w * 8 + j * 32 + (lane >> 3);
            int sc = ((lane & 7) * 8) ^ ((r & 7) << 3);
            gload_lds16(Ksrc + (size_t)r * 512 + k0 + sc, &Bs[(w * 8 + j * 32) * 64]);
        }
        __syncthreads();
#pragma unroll
        for (int kk = 0; kk < 2; ++kk) {
            int kof = kk * 32 + hi * 8;
            int sw = (ln & 7) << 3;
            short8 af[4], bf[4];
#pragma unroll
            for (int mf = 0; mf < 4; ++mf)
                af[mf] = *reinterpret_cast<const short8*>(&As[(wr * 64 + mf * 16 + ln) * 64 + (kof ^ sw)]);
#pragma unroll
            for (int nf = 0; nf < 4; ++nf)
                bf[nf] = *reinterpret_cast<const short8*>(&Bs[(wc * 64 + nf * 16 + ln) * 64 + (kof ^ sw)]);
#pragma unroll
            for (int mf = 0; mf < 4; ++mf)
#pragma unroll
                for (int nf = 0; nf < 4; ++nf)
                    acc[mf][nf] = __builtin_amdgcn_mfma_f32_16x16x32_bf16(af[mf], bf[nf], acc[mf][nf], 0, 0, 0);
        }
        __syncthreads();
    }

    // epilogue: mask (strict j<i), exp, write P bf16, row-sum partials
    short* Ptile = Pc + (size_t)(b * 136 + idx) * 128 * 128;
#pragma unroll
    for (int mf = 0; mf < 4; ++mf) {
        float rs[4] = {0.f, 0.f, 0.f, 0.f};
#pragma unroll
        for (int nf = 0; nf < 4; ++nf)
#pragma unroll
            for (int j = 0; j < 4; ++j) {
                int rl = wr * 64 + mf * 16 + hi * 4 + j;
                int cl = wc * 64 + nf * 16 + ln;
                int irow = m0 + rl, jcol = n0 + cl;
                float p = (jcol < irow) ? __expf(acc[mf][nf][j] * scale) : 0.f;
                short hs = f2bf(p);
                Ptile[(size_t)rl * 128 + cl] = hs;
                rs[j] += bf2f(hs);
            }
#pragma unroll
        for (int j = 0; j < 4; ++j) {
            float s = rs[j];
            s += __shfl_xor(s, 1);
            s += __shfl_xor(s, 2);
            s += __shfl_xor(s, 4);
            s += __shfl_xor(s, 8);
            if (ln == 0) psum[wc][wr * 64 + mf * 16 + hi * 4 + j] = s;
        }
    }
    __syncthreads();
    if (tid < 128)
        Dpart[((size_t)b * 16 + tj) * 2048 + m0 + tid] = psum[0][tid] + psum[1][tid];
}

// ---------------------------------------------------------------- PB: PV pass (R8-exact)
__global__ __launch_bounds__(256) void pv_pass(
    const short* __restrict__ Pc, const short* __restrict__ VtG,
    const float* __restrict__ Dpart, float* __restrict__ Out)
{
    __shared__ short SMEM[128 * 64 + 64 * 64];   // As (P) | Bs (V^T)
    __shared__ float dnm[128];
    short* As = SMEM;
    short* Bs = SMEM + 128 * 64;

    int bid = blockIdx.x;
    int b = bid & 7;
    int rr = bid >> 3;
    int grp = rr >> 5, off = rr & 31;
    int ti = (grp & 1) ? (15 - (off >> 1)) : (off >> 1);
    int colhalf = 2 * grp + (off & 1);
    int m0 = ti * 128, n0 = colhalf * 64;

    int tid = threadIdx.x;
    int w = tid >> 6, lane = tid & 63;
    int wr = w >> 1, wc = w & 1;
    int ln = lane & 15, hi = lane >> 4;

    if (tid < 128) {
        float s = 0.f;
        for (int tj = 0; tj <= ti; ++tj)
            s += Dpart[((size_t)b * 16 + tj) * 2048 + m0 + tid];
        int gi = m0 + tid;
        dnm[tid] = (gi == 0) ? 0.f : 1.0f / s;
    }

    const short* Ptiles = Pc + (size_t)(b * 136 + ti * (ti + 1) / 2) * 128 * 128;
    const short* Vsrc = VtG + (size_t)b * 512 * 2048 + (size_t)n0 * 2048;

    f32x4 acc[4][2];
#pragma unroll
    for (int i = 0; i < 4; ++i)
#pragma unroll
        for (int j = 0; j < 2; ++j) acc[i][j] = {0.f, 0.f, 0.f, 0.f};

    for (int ks = 0; ks < 2 * (ti + 1); ++ks) {
        int tj = ks >> 1;
        int j0 = (ks & 1) * 64;
        const short* Pt = Ptiles + (size_t)tj * 128 * 128;
#pragma unroll
        for (int j = 0; j < 4; ++j) {
            int r = w * 8 + j * 32 + (lane >> 3);
            int sc = ((lane & 7) * 8) ^ ((r & 7) << 3);
            gload_lds16(Pt + (size_t)r * 128 + j0 + sc, &As[(w * 8 + j * 32) * 64]);
        }
#pragma unroll
        for (int j = 0; j < 2; ++j) {
            int r = w * 8 + j * 32 + (lane >> 3);
            int sc = ((lane & 7) * 8) ^ ((r & 7) << 3);
            gload_lds16(Vsrc + (size_t)r * 2048 + tj * 128 + j0 + sc, &Bs[(w * 8 + j * 32) * 64]);
        }
        __syncthreads();
#pragma unroll
        for (int kk = 0; kk < 2; ++kk) {
            int kof = kk * 32 + hi * 8;
            int sw = (ln & 7) << 3;
            short8 af[4], bf[2];
#pragma unroll
            for (int mf = 0; mf < 4; ++mf)
                af[mf] = *reinterpret_cast<const short8*>(&As[(wr * 64 + mf * 16 + ln) * 64 + (kof ^ sw)]);
#pragma unroll
            for (int nf = 0; nf < 2; ++nf)
                bf[nf] = *reinterpret_cast<const short8*>(&Bs[(wc * 32 + nf * 16 + ln) * 64 + (kof ^ sw)]);
#pragma unroll
            for (int mf = 0; mf < 4; ++mf)
#pragma unroll
                for (int nf = 0; nf < 2; ++nf)
                    acc[mf][nf] = __builtin_amdgcn_mfma_f32_16x16x32_bf16(af[mf], bf[nf], acc[mf][nf], 0, 0, 0);
        }
        __syncthreads();
    }

    // epilogue: scale by 1/denom, store fp32
#pragma unroll
    for (int mf = 0; mf < 4; ++mf)
#pragma unroll
        for (int j = 0; j < 4; ++j) {
            int rl = wr * 64 + mf * 16 + hi * 4 + j;
            float rd = dnm[rl];
            float* orow = Out + ((size_t)b * 2048 + m0 + rl) * 512 + n0 + wc * 32 + ln;
#pragma unroll
            for (int nf = 0; nf < 2; ++nf)
                orow[nf * 16] = acc[mf][nf][j] * rd;
        }
}

// ---------------------------------------------------------------- launch
extern "C" void kernel_launch(void* const* d_in, const int* in_sizes, int n_in,
                              void* d_out, int out_size, void* d_ws, size_t ws_size,
                              hipStream_t stream) {
    const float* X  = (const float*)d_in[0];
    const float* Wq = (const float*)d_in[1];
    const float* Wv = (const float*)d_in[2];
    const float* Wk = (const float*)d_in[3];
    float* Out = (float*)d_out;

    char* ws = (char*)d_ws;
    const size_t WT_BYTES  = (size_t)3 * 512 * 512 * 2;        // 1.5 MB
    const size_t MAT_BYTES = (size_t)16384 * 512 * 2;          // 16 MB each
    const size_t PC_BYTES  = (size_t)8 * 136 * 128 * 128 * 2;  // 34.9 MB
    short* Wt = (short*)ws;
    short* Qb = (short*)(ws + WT_BYTES);
    short* Kb = (short*)(ws + WT_BYTES + MAT_BYTES);
    short* Vt = (short*)(ws + WT_BYTES + 2 * MAT_BYTES);
    short* Pc = (short*)(ws + WT_BYTES + 3 * MAT_BYTES);
    short* Xb = Pc;                       // alias: Xb dead before score_pass writes Pc
    float* Dp = (float*)(ws + WT_BYTES + 3 * MAT_BYTES + PC_BYTES);

    fused_prep<<<4288, 256, 0, stream>>>(X, Wq, Wv, Wk, Xb, Wt);
    qkv_gemm<<<1536, 256, 0, stream>>>(Xb, Wt, Qb, Kb, Vt);
    score_pass<<<1088, 256, 0, stream>>>(Qb, Kb, Pc, Dp);
    pv_pass<<<1024, 256, 0, stream>>>(Pc, Vt, Dp, Out);
}

// Round 21
// 132.621 us; speedup vs baseline: 1.0511x; 1.0511x over previous
//
#include <hip/hip_runtime.h>
#include <stdint.h>

// Round 21 (FINAL): R19-exact — best verified configuration, 132.8us.
//  - fused_prep (R16), qkv_gemm (R9: dbuf + 1 VMBAR/kstep + coalesced epilogue),
//    score_pass / pv_pass (R8).
//  - R20's grid swap reverted (FETCH 29->71MB: R19's launch-order B-sharing was
//    load-bearing; total 132.8->139.4).
// Session: R1 290us -> 132.8us (2.2x). Plateau characterized: ~1.75us/128^2-kstep/CU
// across all kernels (~1.8x the per-CU staged-operand service bound); 12 orthogonal
// single-variable interventions null/negative; MfmaUtil ~12% (structure plateau,
// not HW roofline).

typedef __attribute__((ext_vector_type(4))) float f32x4;
typedef __attribute__((ext_vector_type(8))) short short8;
typedef __attribute__((ext_vector_type(4))) short short4b;

__device__ __forceinline__ short f2bf(float f) {
    union { float f; uint32_t u; } v; v.f = f;
    uint32_t r = (v.u + 0x7FFFu + ((v.u >> 16) & 1u)) >> 16;   // RNE
    return (short)r;
}
__device__ __forceinline__ float bf2f(short s) {
    union { uint32_t u; float f; } v; v.u = ((uint32_t)(uint16_t)s) << 16; return v.f;
}
__device__ __forceinline__ float sigm(float x) { return 1.0f / (1.0f + __expf(-x)); }

__device__ __forceinline__ void gload_lds16(const void* g, void* l) {
    __builtin_amdgcn_global_load_lds(
        (const __attribute__((address_space(1))) void*)g,
        (__attribute__((address_space(3))) void*)l, 16, 0, 0);
}

#define VMBAR() asm volatile("s_waitcnt vmcnt(0)\n\ts_barrier" ::: "memory")

// ---------------------------------------------------------------- K0: convert X + prep weights
__global__ __launch_bounds__(256) void fused_prep(
    const float* __restrict__ X, const float* __restrict__ Wq,
    const float* __restrict__ Wv, const float* __restrict__ Wk,
    short* __restrict__ Xb, short* __restrict__ Wt)
{
    __shared__ float T[64 * 68];
    if (blockIdx.x < 4096) {
        size_t i = (size_t)blockIdx.x * 256 + threadIdx.x;     // 8 floats/thread
        const float4* src = reinterpret_cast<const float4*>(X) + i * 2;
        float4 a = src[0], b = src[1];
        short8 o;
        o[0] = f2bf(a.x); o[1] = f2bf(a.y); o[2] = f2bf(a.z); o[3] = f2bf(a.w);
        o[4] = f2bf(b.x); o[5] = f2bf(b.y); o[6] = f2bf(b.z); o[7] = f2bf(b.w);
        *reinterpret_cast<short8*>(Xb + i * 8) = o;
        return;
    }
    int bid = blockIdx.x - 4096;
    int w = bid >> 6;                 // 0..2
    int tile = bid & 63;
    int n0 = (tile & 7) * 64;
    int k0 = (tile >> 3) * 64;
    const float* W = (w == 0) ? Wq : (w == 1) ? Wv : Wk;
    int t = threadIdx.x;
    int tr = t >> 4, tc = t & 15;
    for (int rr = 0; rr < 4; ++rr) {
        int row = rr * 16 + tr;       // k-local
        float4 v = *reinterpret_cast<const float4*>(&W[(size_t)(k0 + row) * 512 + n0 + tc * 4]);
        T[row * 68 + tc * 4 + 0] = v.x;
        T[row * 68 + tc * 4 + 1] = v.y;
        T[row * 68 + tc * 4 + 2] = v.z;
        T[row * 68 + tc * 4 + 3] = v.w;
    }
    __syncthreads();
    for (int wr = 0; wr < 4; ++wr) {
        int nl = wr * 16 + tr;        // n-local
        short4b o;
        for (int i = 0; i < 4; ++i) o[i] = f2bf(T[(tc * 4 + i) * 68 + nl]);
        *reinterpret_cast<short4b*>(&Wt[((size_t)(w * 512 + n0 + nl)) * 512 + k0 + tc * 4]) = o;
    }
}

// ---------------------------------------------------------------- K2: QKV GEMM (R9 version)
__global__ __launch_bounds__(256, 2) void qkv_gemm(
    const short* __restrict__ Xb,    // [16384][512] bf16
    const short* __restrict__ Wt,    // [3][512 n][512 k] bf16
    short* __restrict__ Qb, short* __restrict__ Kb, short* __restrict__ VtG)
{
    __shared__ short SMEM[2][16384];   // per buf: As[128][64] | Bs[128][64]; buf0 reused as Ts

    int bx = blockIdx.x;
    int mt = bx & 127;
    int y = bx >> 7;
    int w = y >> 2, nt = y & 3;
    int m0 = mt * 128, n0 = nt * 128;

    int tid = threadIdx.x;
    int wv = tid >> 6, lane = tid & 63;
    int wr = wv >> 1, wc = wv & 1;
    int ln = lane & 15, hi = lane >> 4;

    f32x4 acc[4][4];
#pragma unroll
    for (int i = 0; i < 4; ++i)
#pragma unroll
        for (int j = 0; j < 4; ++j) acc[i][j] = {0.f, 0.f, 0.f, 0.f};

    const short* Asrc = Xb + (size_t)m0 * 512;
    const short* Bsrc = Wt + (size_t)w * 512 * 512 + (size_t)n0 * 512;

    int srow = wv * 8 + (lane >> 3);
    int ssc0 = (lane & 7) * 8;

#define QSTAGE(ko, buf)                                                            \
    {                                                                              \
        int _k0 = (ko) * 64;                                                       \
        _Pragma("unroll")                                                          \
        for (int _j = 0; _j < 4; ++_j) {                                           \
            int _r = srow + _j * 32;                                               \
            int _sc = ssc0 ^ ((_r & 7) << 3);                                      \
            gload_lds16(Asrc + (size_t)_r * 512 + _k0 + _sc,                       \
                        &SMEM[buf][(wv * 8 + _j * 32) * 64]);                      \
        }                                                                          \
        _Pragma("unroll")                                                          \
        for (int _j = 0; _j < 4; ++_j) {                                           \
            int _r = srow + _j * 32;                                               \
            int _sc = ssc0 ^ ((_r & 7) << 3);                                      \
            gload_lds16(Bsrc + (size_t)_r * 512 + _k0 + _sc,                       \
                        &SMEM[buf][8192 + (wv * 8 + _j * 32) * 64]);               \
        }                                                                          \
    }

    QSTAGE(0, 0);
    for (int ko = 0; ko < 8; ++ko) {
        VMBAR();                                     // buf[ko&1] staged, all waves aligned
        if (ko + 1 < 8) QSTAGE(ko + 1, (ko + 1) & 1);
        const short* As = SMEM[ko & 1];
        const short* Bs = SMEM[ko & 1] + 8192;
#pragma unroll
        for (int kk = 0; kk < 2; ++kk) {
            int kof = kk * 32 + hi * 8;
            int sw = (ln & 7) << 3;
            short8 af[4], bf[4];
#pragma unroll
            for (int mf = 0; mf < 4; ++mf)
                af[mf] = *reinterpret_cast<const short8*>(&As[(wr * 64 + mf * 16 + ln) * 64 + (kof ^ sw)]);
#pragma unroll
            for (int nf = 0; nf < 4; ++nf)
                bf[nf] = *reinterpret_cast<const short8*>(&Bs[(wc * 64 + nf * 16 + ln) * 64 + (kof ^ sw)]);
#pragma unroll
            for (int mf = 0; mf < 4; ++mf)
#pragma unroll
                for (int nf = 0; nf < 4; ++nf)
                    acc[mf][nf] = __builtin_amdgcn_mfma_f32_16x16x32_bf16(af[mf], bf[nf], acc[mf][nf], 0, 0, 0);
        }
    }
    __syncthreads();                                 // loop done -> SMEM reusable
#undef QSTAGE

    short* Ts = SMEM[0];                             // [128][128] shorts, col ^ ((row&7)<<3)
    if (w < 2) {
        // Q/K: sigmoid -> bf16 -> LDS (swizzled) -> coalesced 16B row stores
#pragma unroll
        for (int mf = 0; mf < 4; ++mf)
#pragma unroll
            for (int nf = 0; nf < 4; ++nf)
#pragma unroll
                for (int j = 0; j < 4; ++j) {
                    int rl = wr * 64 + mf * 16 + hi * 4 + j;
                    int cl = wc * 64 + nf * 16 + ln;
                    Ts[rl * 128 + (cl ^ ((rl & 7) << 3))] = f2bf(sigm(acc[mf][nf][j]));
                }
        __syncthreads();
        short* O = (w == 0) ? Qb : Kb;
        int r = tid >> 1, h = tid & 1;
#pragma unroll
        for (int i = 0; i < 8; ++i) {
            int c8 = h * 64 + i * 8;
            short8 v = *reinterpret_cast<const short8*>(&Ts[r * 128 + (c8 ^ ((r & 7) << 3))]);
            *reinterpret_cast<short8*>(&O[(size_t)(m0 + r) * 512 + n0 + c8]) = v;
        }
    } else {
        // V: transpose via LDS, store Vt[b][d][s]
#pragma unroll
        for (int mf = 0; mf < 4; ++mf)
#pragma unroll
            for (int nf = 0; nf < 4; ++nf)
#pragma unroll
                for (int j = 0; j < 4; ++j) {
                    int ml = wr * 64 + mf * 16 + hi * 4 + j;       // s-local
                    int nl = wc * 64 + nf * 16 + ln;               // d-local
                    Ts[nl * 128 + (ml ^ ((nl & 7) << 3))] = f2bf(sigm(acc[mf][nf][j]));
                }
        __syncthreads();
        int bb = m0 >> 11;
        int s0 = m0 & 2047;
        int d = tid >> 1, h = tid & 1;
#pragma unroll
        for (int i = 0; i < 8; ++i) {
            int s8 = h * 64 + i * 8;
            short8 v = *reinterpret_cast<const short8*>(&Ts[d * 128 + (s8 ^ ((d & 7) << 3))]);
            *reinterpret_cast<short8*>(&VtG[((size_t)(bb * 512 + n0 + d)) * 2048 + s0 + s8]) = v;
        }
    }
}

// ---------------------------------------------------------------- PA: score pass (R8-exact)
__global__ __launch_bounds__(256) void score_pass(
    const short* __restrict__ Qb, const short* __restrict__ Kb,
    short* __restrict__ Pc, float* __restrict__ Dpart)
{
    __shared__ short SMEM[128 * 128];       // As | Bs
    __shared__ float psum[2][128];
    short* As = SMEM;
    short* Bs = SMEM + 128 * 64;

    const float scale = 0.044194173824159216f;   // 1/sqrt(512)

    int bid = blockIdx.x;
    int b = bid & 7;
    int idx = bid >> 3;
    int ti = 0;
    while ((ti + 1) * (ti + 2) / 2 <= idx) ++ti;
    int tj = idx - ti * (ti + 1) / 2;
    int m0 = ti * 128, n0 = tj * 128;

    int tid = threadIdx.x;
    int w = tid >> 6, lane = tid & 63;
    int wr = w >> 1, wc = w & 1;
    int ln = lane & 15, hi = lane >> 4;

    const short* Qsrc = Qb + (size_t)b * 2048 * 512 + (size_t)m0 * 512;
    const short* Ksrc = Kb + (size_t)b * 2048 * 512 + (size_t)n0 * 512;

    f32x4 acc[4][4];
#pragma unroll
    for (int i = 0; i < 4; ++i)
#pragma unroll
        for (int j = 0; j < 4; ++j) acc[i][j] = {0.f, 0.f, 0.f, 0.f};

    for (int ko = 0; ko < 8; ++ko) {
        int k0 = ko * 64;
#pragma unroll
        for (int j = 0; j < 4; ++j) {
            int r = w * 8 + j * 32 + (lane >> 3);
            int sc = ((lane & 7) * 8) ^ ((r & 7) << 3);
            gload_lds16(Qsrc + (size_t)r * 512 + k0 + sc, &As[(w * 8 + j * 32) * 64]);
        }
#pragma unroll
        for (int j = 0; j < 4; ++j) {
            int r = w * 8 + j * 32 + (lane >> 3);
            int sc = ((lane & 7) * 8) ^ ((r & 7) << 3);
            gload_lds16(Ksrc + (size_t)r * 512 + k0 + sc, &Bs[(w * 8 + j * 32) * 64]);
        }
        __syncthreads();
#pragma unroll
        for (int kk = 0; kk < 2; ++kk) {
            int kof = kk * 32 + hi * 8;
            int sw = (ln & 7) << 3;
            short8 af[4], bf[4];
#pragma unroll
            for (int mf = 0; mf < 4; ++mf)
                af[mf] = *reinterpret_cast<const short8*>(&As[(wr * 64 + mf * 16 + ln) * 64 + (kof ^ sw)]);
#pragma unroll
            for (int nf = 0; nf < 4; ++nf)
                bf[nf] = *reinterpret_cast<const short8*>(&Bs[(wc * 64 + nf * 16 + ln) * 64 + (kof ^ sw)]);
#pragma unroll
            for (int mf = 0; mf < 4; ++mf)
#pragma unroll
                for (int nf = 0; nf < 4; ++nf)
                    acc[mf][nf] = __builtin_amdgcn_mfma_f32_16x16x32_bf16(af[mf], bf[nf], acc[mf][nf], 0, 0, 0);
        }
        __syncthreads();
    }

    // epilogue: mask (strict j<i), exp, write P bf16, row-sum partials
    short* Ptile = Pc + (size_t)(b * 136 + idx) * 128 * 128;
#pragma unroll
    for (int mf = 0; mf < 4; ++mf) {
        float rs[4] = {0.f, 0.f, 0.f, 0.f};
#pragma unroll
        for (int nf = 0; nf < 4; ++nf)
#pragma unroll
            for (int j = 0; j < 4; ++j) {
                int rl = wr * 64 + mf * 16 + hi * 4 + j;
                int cl = wc * 64 + nf * 16 + ln;
                int irow = m0 + rl, jcol = n0 + cl;
                float p = (jcol < irow) ? __expf(acc[mf][nf][j] * scale) : 0.f;
                short hs = f2bf(p);
                Ptile[(size_t)rl * 128 + cl] = hs;
                rs[j] += bf2f(hs);
            }
#pragma unroll
        for (int j = 0; j < 4; ++j) {
            float s = rs[j];
            s += __shfl_xor(s, 1);
            s += __shfl_xor(s, 2);
            s += __shfl_xor(s, 4);
            s += __shfl_xor(s, 8);
            if (ln == 0) psum[wc][wr * 64 + mf * 16 + hi * 4 + j] = s;
        }
    }
    __syncthreads();
    if (tid < 128)
        Dpart[((size_t)b * 16 + tj) * 2048 + m0 + tid] = psum[0][tid] + psum[1][tid];
}

// ---------------------------------------------------------------- PB: PV pass (R8-exact)
__global__ __launch_bounds__(256) void pv_pass(
    const short* __restrict__ Pc, const short* __restrict__ VtG,
    const float* __restrict__ Dpart, float* __restrict__ Out)
{
    __shared__ short SMEM[128 * 64 + 64 * 64];   // As (P) | Bs (V^T)
    __shared__ float dnm[128];
    short* As = SMEM;
    short* Bs = SMEM + 128 * 64;

    int bid = blockIdx.x;
    int b = bid & 7;
    int rr = bid >> 3;
    int grp = rr >> 5, off = rr & 31;
    int ti = (grp & 1) ? (15 - (off >> 1)) : (off >> 1);
    int colhalf = 2 * grp + (off & 1);
    int m0 = ti * 128, n0 = colhalf * 64;

    int tid = threadIdx.x;
    int w = tid >> 6, lane = tid & 63;
    int wr = w >> 1, wc = w & 1;
    int ln = lane & 15, hi = lane >> 4;

    if (tid < 128) {
        float s = 0.f;
        for (int tj = 0; tj <= ti; ++tj)
            s += Dpart[((size_t)b * 16 + tj) * 2048 + m0 + tid];
        int gi = m0 + tid;
        dnm[tid] = (gi == 0) ? 0.f : 1.0f / s;
    }

    const short* Ptiles = Pc + (size_t)(b * 136 + ti * (ti + 1) / 2) * 128 * 128;
    const short* Vsrc = VtG + (size_t)b * 512 * 2048 + (size_t)n0 * 2048;

    f32x4 acc[4][2];
#pragma unroll
    for (int i = 0; i < 4; ++i)
#pragma unroll
        for (int j = 0; j < 2; ++j) acc[i][j] = {0.f, 0.f, 0.f, 0.f};

    for (int ks = 0; ks < 2 * (ti + 1); ++ks) {
        int tj = ks >> 1;
        int j0 = (ks & 1) * 64;
        const short* Pt = Ptiles + (size_t)tj * 128 * 128;
#pragma unroll
        for (int j = 0; j < 4; ++j) {
            int r = w * 8 + j * 32 + (lane >> 3);
            int sc = ((lane & 7) * 8) ^ ((r & 7) << 3);
            gload_lds16(Pt + (size_t)r * 128 + j0 + sc, &As[(w * 8 + j * 32) * 64]);
        }
#pragma unroll
        for (int j = 0; j < 2; ++j) {
            int r = w * 8 + j * 32 + (lane >> 3);
            int sc = ((lane & 7) * 8) ^ ((r & 7) << 3);
            gload_lds16(Vsrc + (size_t)r * 2048 + tj * 128 + j0 + sc, &Bs[(w * 8 + j * 32) * 64]);
        }
        __syncthreads();
#pragma unroll
        for (int kk = 0; kk < 2; ++kk) {
            int kof = kk * 32 + hi * 8;
            int sw = (ln & 7) << 3;
            short8 af[4], bf[2];
#pragma unroll
            for (int mf = 0; mf < 4; ++mf)
                af[mf] = *reinterpret_cast<const short8*>(&As[(wr * 64 + mf * 16 + ln) * 64 + (kof ^ sw)]);
#pragma unroll
            for (int nf = 0; nf < 2; ++nf)
                bf[nf] = *reinterpret_cast<const short8*>(&Bs[(wc * 32 + nf * 16 + ln) * 64 + (kof ^ sw)]);
#pragma unroll
            for (int mf = 0; mf < 4; ++mf)
#pragma unroll
                for (int nf = 0; nf < 2; ++nf)
                    acc[mf][nf] = __builtin_amdgcn_mfma_f32_16x16x32_bf16(af[mf], bf[nf], acc[mf][nf], 0, 0, 0);
        }
        __syncthreads();
    }

    // epilogue: scale by 1/denom, store fp32
#pragma unroll
    for (int mf = 0; mf < 4; ++mf)
#pragma unroll
        for (int j = 0; j < 4; ++j) {
            int rl = wr * 64 + mf * 16 + hi * 4 + j;
            float rd = dnm[rl];
            float* orow = Out + ((size_t)b * 2048 + m0 + rl) * 512 + n0 + wc * 32 + ln;
#pragma unroll
            for (int nf = 0; nf < 2; ++nf)
                orow[nf * 16] = acc[mf][nf][j] * rd;
        }
}

// ---------------------------------------------------------------- launch
extern "C" void kernel_launch(void* const* d_in, const int* in_sizes, int n_in,
                              void* d_out, int out_size, void* d_ws, size_t ws_size,
                              hipStream_t stream) {
    const float* X  = (const float*)d_in[0];
    const float* Wq = (const float*)d_in[1];
    const float* Wv = (const float*)d_in[2];
    const float* Wk = (const float*)d_in[3];
    float* Out = (float*)d_out;

    char* ws = (char*)d_ws;
    const size_t WT_BYTES  = (size_t)3 * 512 * 512 * 2;        // 1.5 MB
    const size_t MAT_BYTES = (size_t)16384 * 512 * 2;          // 16 MB each
    const size_t PC_BYTES  = (size_t)8 * 136 * 128 * 128 * 2;  // 34.9 MB
    short* Wt = (short*)ws;
    short* Qb = (short*)(ws + WT_BYTES);
    short* Kb = (short*)(ws + WT_BYTES + MAT_BYTES);
    short* Vt = (short*)(ws + WT_BYTES + 2 * MAT_BYTES);
    short* Pc = (short*)(ws + WT_BYTES + 3 * MAT_BYTES);
    short* Xb = Pc;                       // alias: Xb dead before score_pass writes Pc
    float* Dp = (float*)(ws + WT_BYTES + 3 * MAT_BYTES + PC_BYTES);

    fused_prep<<<4288, 256, 0, stream>>>(X, Wq, Wv, Wk, Xb, Wt);
    qkv_gemm<<<1536, 256, 0, stream>>>(Xb, Wt, Qb, Kb, Vt);
    score_pass<<<1088, 256, 0, stream>>>(Qb, Kb, Pc, Dp);
    pv_pass<<<1024, 256, 0, stream>>>(Pc, Vt, Dp, Out);
}